// Round 1
// baseline (885.537 us; speedup 1.0000x reference)
//
#include <hip/hip_runtime.h>

#define NN 50000      // nodes
#define NE 800000     // edges
#define ND 128        // node_attr_dim
#define ED 16         // edge_attr_dim
#define HID 300       // hidden

// ---------------------------------------------------------------- CSR build
__global__ void hist_kernel(const int* __restrict__ ei, int* __restrict__ rowptr) {
    int e = blockIdx.x * blockDim.x + threadIdx.x;
    if (e < NE) {
        int d = ei[NE + e];            // dst = edge_index[1]
        atomicAdd(&rowptr[d + 1], 1);
    }
}

__global__ __launch_bounds__(1024) void scan_kernel(int* __restrict__ rowptr,
                                                    int* __restrict__ cursor) {
    __shared__ int sums[1024];
    const int T = 1024;
    int t = threadIdx.x;
    const int CH = (NN + T - 1) / T;   // 49
    int lo = 1 + t * CH;
    int hi = min(1 + NN, lo + CH);
    int s = 0;
    for (int i = lo; i < hi; ++i) s += rowptr[i];
    sums[t] = s;
    __syncthreads();
    for (int off = 1; off < T; off <<= 1) {
        int v = 0;
        if (t >= off) v = sums[t - off];
        __syncthreads();
        if (t >= off) sums[t] += v;
        __syncthreads();
    }
    int run = sums[t] - s;             // exclusive prefix of chunk
    for (int i = lo; i < hi; ++i) {
        run += rowptr[i];
        rowptr[i] = run;
        if (i < NN) cursor[i] = run;
    }
    if (t == 0) cursor[0] = 0;
}

__global__ void fill_kernel(const int* __restrict__ ei, const float* __restrict__ ew,
                            int* __restrict__ cursor, int* __restrict__ csr_src,
                            float* __restrict__ csr_w, int* __restrict__ csr_eid) {
    int e = blockIdx.x * blockDim.x + threadIdx.x;
    if (e < NE) {
        int d = ei[NE + e];
        int pos = atomicAdd(&cursor[d], 1);
        csr_src[pos] = ei[e];          // src = edge_index[0]
        csr_w[pos]   = ew[e];
        csr_eid[pos] = e;
    }
}

// ------------------------------------------------ inc = seg_sum(w * edge_attr)
__global__ void inc_kernel(const float* __restrict__ edge_attr,
                           const int* __restrict__ rowptr,
                           const float* __restrict__ csr_w,
                           const int* __restrict__ csr_eid,
                           float* __restrict__ inc) {
    int tid = blockIdx.x * blockDim.x + threadIdx.x;
    int n = tid >> 4;
    int j = tid & 15;
    if (n >= NN) return;
    int lo = rowptr[n], hi = rowptr[n + 1];
    float s = 0.f;
    for (int k = lo; k < hi; ++k) {
        float w = csr_w[k];
        int eid = csr_eid[k];
        s += w * edge_attr[eid * ED + j];
    }
    inc[n * ED + j] = s;
}

// -------------------------------------------------------------- tiled GEMM
// C[M,HID] = act( A[M,K] @ B[K,HID] + bias (+ RES) ), MODE 0: A = [x|inc]
#define BM 64
#define BN 64
#define BK 16

template <int MODE>
__global__ __launch_bounds__(256) void gemm_kernel(
    const float* __restrict__ A,     // MODE=1: agg [M,HID]
    const float* __restrict__ X,     // MODE=0: x [M,ND]
    const float* __restrict__ INC,   // MODE=0: inc [M,ED]
    const float* __restrict__ B,     // [K,HID]
    const float* __restrict__ bias,  // [HID]
    const float* __restrict__ RES,   // MODE=1: h0 [M,HID]
    float* __restrict__ C, int M, int K)
{
    __shared__ float As[BK][BM + 4];
    __shared__ float Bs[BK][BN + 4];
    int tid = threadIdx.x;
    int m0 = blockIdx.x * BM;
    int n0 = blockIdx.y * BN;
    int tx = tid & 15, ty = tid >> 4;
    float acc[4][4] = {};
    int ktiles = (K + BK - 1) / BK;
    for (int kt = 0; kt < ktiles; ++kt) {
        int kbase = kt * BK;
        // A tile: thread loads (m = tid>>4 + 16i, k = tid&15)
        {
            int k = tid & 15;
            int kg = kbase + k;
            #pragma unroll
            for (int i = 0; i < 4; ++i) {
                int m = (tid >> 4) + i * 16;
                int mg = m0 + m;
                float v = 0.f;
                if (mg < M && kg < K) {
                    if (MODE == 0)
                        v = (kg < ND) ? X[(size_t)mg * ND + kg]
                                      : INC[(size_t)mg * ED + (kg - ND)];
                    else
                        v = A[(size_t)mg * HID + kg];
                }
                As[k][m] = v;
            }
        }
        // B tile: thread loads (k = tid>>6 + 4i, n = tid&63)
        {
            int n = tid & 63;
            int ng = n0 + n;
            #pragma unroll
            for (int i = 0; i < 4; ++i) {
                int k = (tid >> 6) + i * 4;
                int kg = kbase + k;
                float v = 0.f;
                if (kg < K && ng < HID) v = B[(size_t)kg * HID + ng];
                Bs[k][n] = v;
            }
        }
        __syncthreads();
        #pragma unroll
        for (int kk = 0; kk < BK; ++kk) {
            float a[4], b[4];
            *(float4*)a = *(const float4*)&As[kk][ty * 4];
            *(float4*)b = *(const float4*)&Bs[kk][tx * 4];
            #pragma unroll
            for (int i = 0; i < 4; ++i)
                #pragma unroll
                for (int j = 0; j < 4; ++j)
                    acc[i][j] += a[i] * b[j];
        }
        __syncthreads();
    }
    #pragma unroll
    for (int i = 0; i < 4; ++i) {
        int mg = m0 + ty * 4 + i;
        if (mg >= M) continue;
        #pragma unroll
        for (int j = 0; j < 4; ++j) {
            int ng = n0 + tx * 4 + j;
            if (ng >= HID) continue;
            float v = acc[i][j] + bias[ng];
            if (MODE == 1) v += RES[(size_t)mg * HID + ng];
            v = fmaxf(v, 0.f);
            C[(size_t)mg * HID + ng] = v;
        }
    }
}

// ------------------------------------- agg[n] = mean_k w_k * h0[src_k]
__global__ __launch_bounds__(256) void agg_kernel(
    const float* __restrict__ h0,
    const int* __restrict__ rowptr,
    const int* __restrict__ csr_src,
    const float* __restrict__ csr_w,
    float* __restrict__ agg)
{
    int wave = (blockIdx.x * blockDim.x + threadIdx.x) >> 6;
    int lane = threadIdx.x & 63;
    if (wave >= NN) return;
    int n = wave;
    int lo = rowptr[n], hi = rowptr[n + 1];
    float acc[5] = {0.f, 0.f, 0.f, 0.f, 0.f};
    for (int k = lo; k < hi; ++k) {
        int s = csr_src[k];
        float w = csr_w[k];
        const float* row = h0 + (size_t)s * HID;
        #pragma unroll
        for (int j = 0; j < 5; ++j) {
            int c = lane + j * 64;
            if (c < HID) acc[j] += w * row[c];
        }
    }
    float invd = 1.f / fmaxf((float)(hi - lo), 1.f);
    #pragma unroll
    for (int j = 0; j < 5; ++j) {
        int c = lane + j * 64;
        if (c < HID) agg[(size_t)n * HID + c] = acc[j] * invd;
    }
}

// ---------------------------------------------------------------- launch
extern "C" void kernel_launch(void* const* d_in, const int* in_sizes, int n_in,
                              void* d_out, int out_size, void* d_ws, size_t ws_size,
                              hipStream_t stream) {
    const float* x           = (const float*)d_in[0];
    const float* edge_attr   = (const float*)d_in[1];
    const float* edge_weight = (const float*)d_in[2];
    // d_in[3] node_weight unused (isLastLayer=False)
    const float* W0 = (const float*)d_in[4];
    const float* b0 = (const float*)d_in[5];
    const float* W  = (const float*)d_in[6];
    const float* b  = (const float*)d_in[7];
    const int* ei   = (const int*)d_in[8];

    float* out = (float*)d_out;
    float* h  = out;                          // output 0: [NN, HID]
    float* h0 = out + (size_t)NN * HID;       // output 1: [NN, HID]

    // workspace layout
    int*   rowptr  = (int*)d_ws;                          // NN+1
    int*   cursor  = rowptr + (NN + 64);                  // NN
    int*   csr_src = cursor + (NN + 64);                  // NE
    float* csr_w   = (float*)(csr_src + NE);              // NE
    int*   csr_eid = (int*)(csr_w + NE);                  // NE
    float* inc     = (float*)(csr_eid + NE);              // NN*ED
    float* agg     = inc + (size_t)NN * ED;               // NN*HID
    // total ~73.5 MB

    hipMemsetAsync(rowptr, 0, (NN + 1) * sizeof(int), stream);
    hist_kernel<<<(NE + 255) / 256, 256, 0, stream>>>(ei, rowptr);
    scan_kernel<<<1, 1024, 0, stream>>>(rowptr, cursor);
    fill_kernel<<<(NE + 255) / 256, 256, 0, stream>>>(ei, edge_weight, cursor,
                                                      csr_src, csr_w, csr_eid);
    inc_kernel<<<(NN * 16 + 255) / 256, 256, 0, stream>>>(edge_attr, rowptr,
                                                          csr_w, csr_eid, inc);
    dim3 g1((NN + BM - 1) / BM, (HID + BN - 1) / BN);
    gemm_kernel<0><<<g1, 256, 0, stream>>>(nullptr, x, inc, W0, b0, nullptr,
                                           h0, NN, ND + ED);
    agg_kernel<<<(NN + 3) / 4, 256, 0, stream>>>(h0, rowptr, csr_src, csr_w, agg);
    gemm_kernel<1><<<g1, 256, 0, stream>>>(agg, nullptr, nullptr, W, b, h0,
                                           h, NN, HID);
}

// Round 2
// 676.303 us; speedup vs baseline: 1.3094x; 1.3094x over previous
//
#include <hip/hip_runtime.h>

#define NN 50000      // nodes
#define NE 800000     // edges
#define ND 128        // node_attr_dim
#define ED 16         // edge_attr_dim
#define HID 300       // hidden
#define KP1 192       // padded K for gemm1 (128+16 -> 192)
#define KP2 320       // padded K for gemm2 (300 -> 320)
#define NP 320        // padded N (300 -> 320)

typedef __attribute__((ext_vector_type(8))) short short8;
typedef __attribute__((ext_vector_type(4))) float f32x4;

__device__ __forceinline__ unsigned short f2b(float f) {
    unsigned int u = __float_as_uint(f);
    u = (u + 0x7FFFu + ((u >> 16) & 1u)) >> 16;   // RNE
    return (unsigned short)u;
}
__device__ __forceinline__ float b2f(unsigned short u) {
    return __uint_as_float(((unsigned int)u) << 16);
}

// ---------------------------------------------------------------- CSR build
__global__ void hist_kernel(const int* __restrict__ ei, int* __restrict__ rowptr) {
    int e = blockIdx.x * blockDim.x + threadIdx.x;
    if (e < NE) atomicAdd(&rowptr[ei[NE + e] + 1], 1);
}

__global__ __launch_bounds__(1024) void scan_kernel(int* __restrict__ rowptr,
                                                    int* __restrict__ cursor) {
    __shared__ int sums[1024];
    const int T = 1024;
    int t = threadIdx.x;
    const int CH = (NN + T - 1) / T;
    int lo = 1 + t * CH;
    int hi = min(1 + NN, lo + CH);
    int s = 0;
    for (int i = lo; i < hi; ++i) s += rowptr[i];
    sums[t] = s;
    __syncthreads();
    for (int off = 1; off < T; off <<= 1) {
        int v = 0;
        if (t >= off) v = sums[t - off];
        __syncthreads();
        if (t >= off) sums[t] += v;
        __syncthreads();
    }
    int run = sums[t] - s;
    for (int i = lo; i < hi; ++i) {
        run += rowptr[i];
        rowptr[i] = run;
        if (i < NN) cursor[i] = run;
    }
    if (t == 0) cursor[0] = 0;
}

__global__ void fill_kernel(const int* __restrict__ ei, const float* __restrict__ ew,
                            int* __restrict__ cursor, int* __restrict__ csr_src,
                            float* __restrict__ csr_w, int* __restrict__ csr_eid) {
    int e = blockIdx.x * blockDim.x + threadIdx.x;
    if (e < NE) {
        int d = ei[NE + e];
        int pos = atomicAdd(&cursor[d], 1);
        csr_src[pos] = ei[e];
        csr_w[pos]   = ew[e];
        csr_eid[pos] = e;
    }
}

// ------------------------------------------------ inc = seg_sum(w * edge_attr)
__global__ void inc_kernel(const float* __restrict__ edge_attr,
                           const int* __restrict__ rowptr,
                           const float* __restrict__ csr_w,
                           const int* __restrict__ csr_eid,
                           float* __restrict__ inc) {
    int tid = blockIdx.x * blockDim.x + threadIdx.x;
    int n = tid >> 4;
    int j = tid & 15;
    if (n >= NN) return;
    int lo = rowptr[n], hi = rowptr[n + 1];
    float s = 0.f;
    for (int k = lo; k < hi; ++k)
        s += csr_w[k] * edge_attr[csr_eid[k] * ED + j];
    inc[n * ED + j] = s;
}

// ------------------------------------------------------- bf16 pack kernels
// A1[n][c] = bf16(c<128 ? x : c<144 ? inc : 0), 192 threads/block, 1 block/row
__global__ void prep_A1(const float* __restrict__ x, const float* __restrict__ inc,
                        unsigned short* __restrict__ A1) {
    int n = blockIdx.x, c = threadIdx.x;
    float v = 0.f;
    if (c < ND) v = x[(size_t)n * ND + c];
    else if (c < ND + ED) v = inc[(size_t)n * ED + (c - ND)];
    A1[(size_t)n * KP1 + c] = f2b(v);
}

// B0T[n][k] = bf16(W0[k][n]) padded to [320][192]
__global__ void castB0(const float* __restrict__ W0, unsigned short* __restrict__ B0T) {
    int n = blockIdx.x, k = threadIdx.x;   // 320 blocks x 192 threads
    float v = (n < HID && k < ND + ED) ? W0[(size_t)k * HID + n] : 0.f;
    B0T[(size_t)n * KP1 + k] = f2b(v);
}

// BT[n][k] = bf16(W[k][n]) padded to [320][320]
__global__ void castB(const float* __restrict__ W, unsigned short* __restrict__ BT) {
    int n = blockIdx.x, k = threadIdx.x;   // 320 blocks x 320 threads
    float v = (n < HID && k < HID) ? W[(size_t)k * HID + n] : 0.f;
    BT[(size_t)n * KP2 + k] = f2b(v);
}

// ----------------------------------------------------------- MFMA bf16 GEMM
// C[M,300] = relu(A[M,KP] @ B^T[320,KP]^T + bias (+RES)); MODE0 also writes
// bf16 copy h0b[M,320]. BM=128 BN=64 BK=64, 4 waves, 4x2 16x16 tiles/wave.
template <int MODE, int KP>
__global__ __launch_bounds__(256) void gemm_mfma(
    const unsigned short* __restrict__ A,   // [M, KP] bf16 row-major
    const unsigned short* __restrict__ BT,  // [320, KP] bf16 (B transposed)
    const float* __restrict__ bias,         // [300]
    const float* __restrict__ RES,          // MODE1: h0 [M,300] fp32
    float* __restrict__ C,                  // [M,300] fp32
    unsigned short* __restrict__ h0b,       // MODE0: [M,320] bf16
    int M)
{
    __shared__ unsigned short As[128][64];
    __shared__ unsigned short Bs[64][64];
    const int tid = threadIdx.x;
    const int m0 = blockIdx.x * 128;
    const int n0 = blockIdx.y * 64;
    const int wave = tid >> 6, lane = tid & 63;
    const int wm = wave >> 1, wn = wave & 1;
    const int quad = lane >> 4, lr = lane & 15;
    f32x4 acc[4][2] = {};

    for (int kb = 0; kb < KP; kb += 64) {
        #pragma unroll
        for (int i = 0; i < 4; ++i) {           // A tile 128x64
            int s = tid + i * 256;
            int r = s >> 3, c = (s & 7) * 8;
            int mg = m0 + r; if (mg >= M) mg = M - 1;
            *(uint4*)&As[r][c] = *(const uint4*)&A[(size_t)mg * KP + kb + c];
        }
        #pragma unroll
        for (int i = 0; i < 2; ++i) {           // B tile 64x64
            int s = tid + i * 256;
            int r = s >> 3, c = (s & 7) * 8;
            *(uint4*)&Bs[r][c] = *(const uint4*)&BT[(size_t)(n0 + r) * KP + kb + c];
        }
        __syncthreads();
        #pragma unroll
        for (int ks = 0; ks < 2; ++ks) {
            short8 a[4], b[2];
            #pragma unroll
            for (int tm = 0; tm < 4; ++tm)
                a[tm] = *(const short8*)&As[wm * 64 + tm * 16 + lr][ks * 32 + quad * 8];
            #pragma unroll
            for (int tn = 0; tn < 2; ++tn)
                b[tn] = *(const short8*)&Bs[wn * 32 + tn * 16 + lr][ks * 32 + quad * 8];
            #pragma unroll
            for (int tm = 0; tm < 4; ++tm)
                #pragma unroll
                for (int tn = 0; tn < 2; ++tn)
                    acc[tm][tn] = __builtin_amdgcn_mfma_f32_16x16x32_bf16(
                        a[tm], b[tn], acc[tm][tn], 0, 0, 0);
        }
        __syncthreads();
    }
    #pragma unroll
    for (int tm = 0; tm < 4; ++tm) {
        #pragma unroll
        for (int tn = 0; tn < 2; ++tn) {
            int ng = n0 + wn * 32 + tn * 16 + lr;
            #pragma unroll
            for (int r = 0; r < 4; ++r) {
                int mg = m0 + wm * 64 + tm * 16 + quad * 4 + r;
                if (mg < M && ng < HID) {
                    float v = acc[tm][tn][r] + bias[ng];
                    if (MODE == 1) v += RES[(size_t)mg * HID + ng];
                    v = fmaxf(v, 0.f);
                    C[(size_t)mg * HID + ng] = v;
                    if (MODE == 0) h0b[(size_t)mg * NP + ng] = f2b(v);
                }
            }
        }
    }
}

// ------------------- aggB[n] = bf16(mean_k w_k * h0b[src_k]), padded to 320
__global__ __launch_bounds__(256) void agg_kernel(
    const unsigned short* __restrict__ h0b,   // [NN, 320] bf16 (cols<300 valid)
    const int* __restrict__ rowptr,
    const int* __restrict__ csr_src,
    const float* __restrict__ csr_w,
    unsigned short* __restrict__ aggB)        // [NN, 320] bf16, pad cols = 0
{
    int n = (blockIdx.x * blockDim.x + threadIdx.x) >> 6;
    int lane = threadIdx.x & 63;
    if (n >= NN) return;
    int lo = rowptr[n], hi = rowptr[n + 1];
    float acc[5] = {0.f, 0.f, 0.f, 0.f, 0.f};
    for (int k = lo; k < hi; ++k) {
        int s = csr_src[k];
        float w = csr_w[k];
        const unsigned short* row = h0b + (size_t)s * NP;
        #pragma unroll
        for (int j = 0; j < 5; ++j) {
            int c = lane + j * 64;
            if (c < HID) acc[j] += w * b2f(row[c]);
        }
    }
    float invd = 1.f / fmaxf((float)(hi - lo), 1.f);
    #pragma unroll
    for (int j = 0; j < 5; ++j) {
        int c = lane + j * 64;
        aggB[(size_t)n * NP + c] = (c < HID) ? f2b(acc[j] * invd) : (unsigned short)0;
    }
}

// ---------------------------------------------------------------- launch
extern "C" void kernel_launch(void* const* d_in, const int* in_sizes, int n_in,
                              void* d_out, int out_size, void* d_ws, size_t ws_size,
                              hipStream_t stream) {
    const float* x           = (const float*)d_in[0];
    const float* edge_attr   = (const float*)d_in[1];
    const float* edge_weight = (const float*)d_in[2];
    const float* W0 = (const float*)d_in[4];
    const float* b0 = (const float*)d_in[5];
    const float* W  = (const float*)d_in[6];
    const float* b  = (const float*)d_in[7];
    const int* ei   = (const int*)d_in[8];

    float* out = (float*)d_out;
    float* h  = out;                          // output 0: [NN, HID]
    float* h0 = out + (size_t)NN * HID;       // output 1: [NN, HID]

    // ---- workspace layout (bytes, 256-aligned chunks) ----
    char* p = (char*)d_ws;
    auto alloc = [&](size_t bytes) { char* q = p; p += (bytes + 255) & ~(size_t)255; return q; };
    int*   rowptr  = (int*)  alloc((NN + 1) * sizeof(int));
    int*   cursor  = (int*)  alloc(NN * sizeof(int));
    int*   csr_src = (int*)  alloc(NE * sizeof(int));
    float* csr_w   = (float*)alloc(NE * sizeof(float));
    int*   csr_eid = (int*)  alloc(NE * sizeof(int));
    float* inc     = (float*)alloc((size_t)NN * ED * sizeof(float));
    unsigned short* A1   = (unsigned short*)alloc((size_t)NN * KP1 * 2);
    unsigned short* h0b  = (unsigned short*)alloc((size_t)NN * NP * 2);
    unsigned short* aggB = (unsigned short*)alloc((size_t)NN * NP * 2);
    unsigned short* B0T  = (unsigned short*)alloc((size_t)NP * KP1 * 2);
    unsigned short* BT   = (unsigned short*)alloc((size_t)NP * KP2 * 2);
    // total ~97 MB

    hipMemsetAsync(rowptr, 0, (NN + 1) * sizeof(int), stream);
    hist_kernel<<<(NE + 255) / 256, 256, 0, stream>>>(ei, rowptr);
    scan_kernel<<<1, 1024, 0, stream>>>(rowptr, cursor);
    fill_kernel<<<(NE + 255) / 256, 256, 0, stream>>>(ei, edge_weight, cursor,
                                                      csr_src, csr_w, csr_eid);
    inc_kernel<<<(NN * 16 + 255) / 256, 256, 0, stream>>>(edge_attr, rowptr,
                                                          csr_w, csr_eid, inc);
    castB0<<<NP, KP1, 0, stream>>>(W0, B0T);
    castB<<<NP, KP2, 0, stream>>>(W, BT);
    prep_A1<<<NN, KP1, 0, stream>>>(x, inc, A1);

    dim3 g((NN + 127) / 128, NP / 64);
    gemm_mfma<0, KP1><<<g, 256, 0, stream>>>(A1, B0T, b0, nullptr, h0, h0b, NN);
    agg_kernel<<<(NN + 3) / 4, 256, 0, stream>>>(h0b, rowptr, csr_src, csr_w, aggB);
    gemm_mfma<1, KP2><<<g, 256, 0, stream>>>(aggB, BT, b, h0, h, nullptr, NN);
}

// Round 3
// 665.439 us; speedup vs baseline: 1.3308x; 1.0163x over previous
//
#include <hip/hip_runtime.h>

#define NN 50000      // nodes
#define NE 800000     // edges
#define ND 128        // node_attr_dim
#define ED 16         // edge_attr_dim
#define HID 300       // hidden
#define KP1 192       // padded K for gemm1 (128+16 -> 192)
#define KP2 320       // padded K for gemm2 (300 -> 320)
#define NP 320        // padded N (300 -> 320)

typedef __attribute__((ext_vector_type(8))) short short8;
typedef __attribute__((ext_vector_type(4))) float f32x4;

__device__ __forceinline__ unsigned short f2b(float f) {
    unsigned int u = __float_as_uint(f);
    u = (u + 0x7FFFu + ((u >> 16) & 1u)) >> 16;   // RNE
    return (unsigned short)u;
}
__device__ __forceinline__ float b2f(unsigned short u) {
    return __uint_as_float(((unsigned int)u) << 16);
}
__device__ __forceinline__ float blo(unsigned int u) {   // low bf16 of pair
    return __uint_as_float(u << 16);
}
__device__ __forceinline__ float bhi(unsigned int u) {   // high bf16 of pair
    return __uint_as_float(u & 0xffff0000u);
}

// ---------------------------------------------------------------- CSR build
__global__ void hist_kernel(const int* __restrict__ ei, int* __restrict__ rowptr) {
    int e = blockIdx.x * blockDim.x + threadIdx.x;
    if (e < NE) atomicAdd(&rowptr[ei[NE + e] + 1], 1);
}

__global__ __launch_bounds__(1024) void scan_kernel(int* __restrict__ rowptr,
                                                    int* __restrict__ cursor) {
    __shared__ int sums[1024];
    const int T = 1024;
    int t = threadIdx.x;
    const int CH = (NN + T - 1) / T;
    int lo = 1 + t * CH;
    int hi = min(1 + NN, lo + CH);
    int s = 0;
    for (int i = lo; i < hi; ++i) s += rowptr[i];
    sums[t] = s;
    __syncthreads();
    for (int off = 1; off < T; off <<= 1) {
        int v = 0;
        if (t >= off) v = sums[t - off];
        __syncthreads();
        if (t >= off) sums[t] += v;
        __syncthreads();
    }
    int run = sums[t] - s;
    for (int i = lo; i < hi; ++i) {
        run += rowptr[i];
        rowptr[i] = run;
        if (i < NN) cursor[i] = run;
    }
    if (t == 0) cursor[0] = 0;
}

__global__ void fill_kernel(const int* __restrict__ ei, const float* __restrict__ ew,
                            int* __restrict__ cursor, int* __restrict__ csr_src,
                            float* __restrict__ csr_w, int* __restrict__ csr_eid) {
    int e = blockIdx.x * blockDim.x + threadIdx.x;
    if (e < NE) {
        int d = ei[NE + e];
        int pos = atomicAdd(&cursor[d], 1);
        csr_src[pos] = ei[e];
        csr_w[pos]   = ew[e];
        csr_eid[pos] = e;
    }
}

// --------------------------- fused: inc seg-sum + bf16 pack of A1 = [x|inc|0]
// block = node, 192 threads. Threads 0..127 cast x; threads 128..143 compute
// the weighted edge_attr segment sum; threads 144..191 write pad zeros.
__global__ __launch_bounds__(192) void prep_A1(
    const float* __restrict__ x,
    const float* __restrict__ edge_attr,
    const int* __restrict__ rowptr,
    const float* __restrict__ csr_w,
    const int* __restrict__ csr_eid,
    unsigned short* __restrict__ A1) {
    int n = blockIdx.x, c = threadIdx.x;
    float v = 0.f;
    if (c < ND) {
        v = x[(size_t)n * ND + c];
    } else if (c < ND + ED) {
        int j = c - ND;
        int lo = rowptr[n], hi = rowptr[n + 1];
        for (int k = lo; k < hi; ++k)
            v += csr_w[k] * edge_attr[csr_eid[k] * ED + j];
    }
    A1[(size_t)n * KP1 + c] = f2b(v);
}

// B0T[n][k] = bf16(W0[k][n]) padded to [320][192]
__global__ void castB0(const float* __restrict__ W0, unsigned short* __restrict__ B0T) {
    int n = blockIdx.x, k = threadIdx.x;
    float v = (n < HID && k < ND + ED) ? W0[(size_t)k * HID + n] : 0.f;
    B0T[(size_t)n * KP1 + k] = f2b(v);
}

// BT[n][k] = bf16(W[k][n]) padded to [320][320]
__global__ void castB(const float* __restrict__ W, unsigned short* __restrict__ BT) {
    int n = blockIdx.x, k = threadIdx.x;
    float v = (n < HID && k < HID) ? W[(size_t)k * HID + n] : 0.f;
    BT[(size_t)n * KP2 + k] = f2b(v);
}

// ----------------------------------------------------------- MFMA bf16 GEMM
template <int MODE, int KP>
__global__ __launch_bounds__(256) void gemm_mfma(
    const unsigned short* __restrict__ A,   // [M, KP] bf16 row-major
    const unsigned short* __restrict__ BT,  // [320, KP] bf16 (B transposed)
    const float* __restrict__ bias,         // [300]
    const float* __restrict__ RES,          // MODE1: h0 [M,300] fp32
    float* __restrict__ C,                  // [M,300] fp32
    unsigned short* __restrict__ h0b,       // MODE0: [M,320] bf16
    int M)
{
    __shared__ unsigned short As[128][64];
    __shared__ unsigned short Bs[64][64];
    const int tid = threadIdx.x;
    const int m0 = blockIdx.x * 128;
    const int n0 = blockIdx.y * 64;
    const int wave = tid >> 6, lane = tid & 63;
    const int wm = wave >> 1, wn = wave & 1;
    const int quad = lane >> 4, lr = lane & 15;
    f32x4 acc[4][2] = {};

    for (int kb = 0; kb < KP; kb += 64) {
        #pragma unroll
        for (int i = 0; i < 4; ++i) {           // A tile 128x64
            int s = tid + i * 256;
            int r = s >> 3, c = (s & 7) * 8;
            int mg = m0 + r; if (mg >= M) mg = M - 1;
            *(uint4*)&As[r][c] = *(const uint4*)&A[(size_t)mg * KP + kb + c];
        }
        #pragma unroll
        for (int i = 0; i < 2; ++i) {           // B tile 64x64
            int s = tid + i * 256;
            int r = s >> 3, c = (s & 7) * 8;
            *(uint4*)&Bs[r][c] = *(const uint4*)&BT[(size_t)(n0 + r) * KP + kb + c];
        }
        __syncthreads();
        #pragma unroll
        for (int ks = 0; ks < 2; ++ks) {
            short8 a[4], b[2];
            #pragma unroll
            for (int tm = 0; tm < 4; ++tm)
                a[tm] = *(const short8*)&As[wm * 64 + tm * 16 + lr][ks * 32 + quad * 8];
            #pragma unroll
            for (int tn = 0; tn < 2; ++tn)
                b[tn] = *(const short8*)&Bs[wn * 32 + tn * 16 + lr][ks * 32 + quad * 8];
            #pragma unroll
            for (int tm = 0; tm < 4; ++tm)
                #pragma unroll
                for (int tn = 0; tn < 2; ++tn)
                    acc[tm][tn] = __builtin_amdgcn_mfma_f32_16x16x32_bf16(
                        a[tm], b[tn], acc[tm][tn], 0, 0, 0);
        }
        __syncthreads();
    }
    #pragma unroll
    for (int tm = 0; tm < 4; ++tm) {
        #pragma unroll
        for (int tn = 0; tn < 2; ++tn) {
            int ng = n0 + wn * 32 + tn * 16 + lr;
            #pragma unroll
            for (int r = 0; r < 4; ++r) {
                int mg = m0 + wm * 64 + tm * 16 + quad * 4 + r;
                if (mg < M && ng < HID) {
                    float v = acc[tm][tn][r] + bias[ng];
                    if (MODE == 1) v += RES[(size_t)mg * HID + ng];
                    v = fmaxf(v, 0.f);
                    C[(size_t)mg * HID + ng] = v;
                    if (MODE == 0) h0b[(size_t)mg * NP + ng] = f2b(v);
                }
            }
        }
    }
}

// ---------------- aggB[n] = bf16(mean_k w_k * h0b[src_k]) ------------------
// One wave per node. Row = 640 B = 40 uint4; lanes 0..39 each own one uint4
// (8 bf16 = cols 8l..8l+7). ONE vmem gather instruction per edge (10 cache
// lines), unrolled x2 for MLP. 8 fp32 accumulators; uint4 store at the end.
__global__ __launch_bounds__(256) void agg_kernel(
    const unsigned short* __restrict__ h0b,   // [NN, 320] bf16
    const int* __restrict__ rowptr,
    const int* __restrict__ csr_src,
    const float* __restrict__ csr_w,
    unsigned short* __restrict__ aggB)        // [NN, 320] bf16, pad cols = 0
{
    int n = (blockIdx.x * blockDim.x + threadIdx.x) >> 6;
    int lane = threadIdx.x & 63;
    if (n >= NN) return;
    int lo = rowptr[n], hi = rowptr[n + 1];
    float acc[8] = {};
    const uint4* h4 = (const uint4*)h0b;      // row stride = 40 uint4
    bool act = lane < 40;
    int k = lo;
    for (; k + 1 < hi; k += 2) {
        int s0 = csr_src[k], s1 = csr_src[k + 1];
        float w0 = csr_w[k], w1 = csr_w[k + 1];
        uint4 r0 = {0, 0, 0, 0}, r1 = {0, 0, 0, 0};
        if (act) {
            r0 = h4[(size_t)s0 * 40 + lane];
            r1 = h4[(size_t)s1 * 40 + lane];
        }
        acc[0] += w0 * blo(r0.x); acc[1] += w0 * bhi(r0.x);
        acc[2] += w0 * blo(r0.y); acc[3] += w0 * bhi(r0.y);
        acc[4] += w0 * blo(r0.z); acc[5] += w0 * bhi(r0.z);
        acc[6] += w0 * blo(r0.w); acc[7] += w0 * bhi(r0.w);
        acc[0] += w1 * blo(r1.x); acc[1] += w1 * bhi(r1.x);
        acc[2] += w1 * blo(r1.y); acc[3] += w1 * bhi(r1.y);
        acc[4] += w1 * blo(r1.z); acc[5] += w1 * bhi(r1.z);
        acc[6] += w1 * blo(r1.w); acc[7] += w1 * bhi(r1.w);
    }
    if (k < hi) {
        int s0 = csr_src[k];
        float w0 = csr_w[k];
        uint4 r0 = {0, 0, 0, 0};
        if (act) r0 = h4[(size_t)s0 * 40 + lane];
        acc[0] += w0 * blo(r0.x); acc[1] += w0 * bhi(r0.x);
        acc[2] += w0 * blo(r0.y); acc[3] += w0 * bhi(r0.y);
        acc[4] += w0 * blo(r0.z); acc[5] += w0 * bhi(r0.z);
        acc[6] += w0 * blo(r0.w); acc[7] += w0 * bhi(r0.w);
    }
    if (act) {
        float invd = 1.f / fmaxf((float)(hi - lo), 1.f);
        int cbase = lane * 8;
        unsigned int o[4];
        #pragma unroll
        for (int i = 0; i < 4; ++i) {
            int c0 = cbase + 2 * i, c1 = c0 + 1;
            unsigned int ulo = (c0 < HID) ? f2b(acc[2 * i] * invd) : 0;
            unsigned int uhi = (c1 < HID) ? f2b(acc[2 * i + 1] * invd) : 0;
            o[i] = ulo | (uhi << 16);
        }
        uint4* a4 = (uint4*)aggB;
        uint4 v; v.x = o[0]; v.y = o[1]; v.z = o[2]; v.w = o[3];
        a4[(size_t)n * 40 + lane] = v;
    }
}

// ---------------------------------------------------------------- launch
extern "C" void kernel_launch(void* const* d_in, const int* in_sizes, int n_in,
                              void* d_out, int out_size, void* d_ws, size_t ws_size,
                              hipStream_t stream) {
    const float* x           = (const float*)d_in[0];
    const float* edge_attr   = (const float*)d_in[1];
    const float* edge_weight = (const float*)d_in[2];
    const float* W0 = (const float*)d_in[4];
    const float* b0 = (const float*)d_in[5];
    const float* W  = (const float*)d_in[6];
    const float* b  = (const float*)d_in[7];
    const int* ei   = (const int*)d_in[8];

    float* out = (float*)d_out;
    float* h  = out;                          // output 0: [NN, HID]
    float* h0 = out + (size_t)NN * HID;       // output 1: [NN, HID]

    char* p = (char*)d_ws;
    auto alloc = [&](size_t bytes) { char* q = p; p += (bytes + 255) & ~(size_t)255; return q; };
    int*   rowptr  = (int*)  alloc((NN + 1) * sizeof(int));
    int*   cursor  = (int*)  alloc(NN * sizeof(int));
    int*   csr_src = (int*)  alloc(NE * sizeof(int));
    float* csr_w   = (float*)alloc(NE * sizeof(float));
    int*   csr_eid = (int*)  alloc(NE * sizeof(int));
    unsigned short* A1   = (unsigned short*)alloc((size_t)NN * KP1 * 2);
    unsigned short* h0b  = (unsigned short*)alloc((size_t)NN * NP * 2);
    unsigned short* aggB = (unsigned short*)alloc((size_t)NN * NP * 2);
    unsigned short* B0T  = (unsigned short*)alloc((size_t)NP * KP1 * 2);
    unsigned short* BT   = (unsigned short*)alloc((size_t)NP * KP2 * 2);

    hipMemsetAsync(rowptr, 0, (NN + 1) * sizeof(int), stream);
    hist_kernel<<<(NE + 255) / 256, 256, 0, stream>>>(ei, rowptr);
    scan_kernel<<<1, 1024, 0, stream>>>(rowptr, cursor);
    fill_kernel<<<(NE + 255) / 256, 256, 0, stream>>>(ei, edge_weight, cursor,
                                                      csr_src, csr_w, csr_eid);
    castB0<<<NP, KP1, 0, stream>>>(W0, B0T);
    castB<<<NP, KP2, 0, stream>>>(W, BT);
    prep_A1<<<NN, 192, 0, stream>>>(x, edge_attr, rowptr, csr_w, csr_eid, A1);

    dim3 g((NN + 127) / 128, NP / 64);
    gemm_mfma<0, KP1><<<g, 256, 0, stream>>>(A1, B0T, b0, nullptr, h0, h0b, NN);
    agg_kernel<<<(NN + 3) / 4, 256, 0, stream>>>(h0b, rowptr, csr_src, csr_w, aggB);
    gemm_mfma<1, KP2><<<g, 256, 0, stream>>>(aggB, BT, b, h0, h, nullptr, NN);
}

// Round 4
// 611.315 us; speedup vs baseline: 1.4486x; 1.0885x over previous
//
#include <hip/hip_runtime.h>

#define NN 50000      // nodes
#define NE 800000     // edges
#define ND 128        // node_attr_dim
#define ED 16         // edge_attr_dim
#define HID 300       // hidden
#define KP1 192       // padded K for gemm1 (128+16 -> 192)
#define KP2 320       // padded K for gemm2 (300 -> 320)
#define NP 320        // padded N (300 -> 320)

typedef __attribute__((ext_vector_type(8))) short short8;
typedef __attribute__((ext_vector_type(4))) float f32x4;

__device__ __forceinline__ unsigned short f2b(float f) {
    unsigned int u = __float_as_uint(f);
    u = (u + 0x7FFFu + ((u >> 16) & 1u)) >> 16;   // RNE
    return (unsigned short)u;
}
__device__ __forceinline__ float blo(unsigned int u) {   // low bf16 of pair
    return __uint_as_float(u << 16);
}
__device__ __forceinline__ float bhi(unsigned int u) {   // high bf16 of pair
    return __uint_as_float(u & 0xffff0000u);
}

// ---------------------------------------------------------------- CSR build
__global__ void hist_kernel(const int* __restrict__ ei, int* __restrict__ rowptr) {
    int e = blockIdx.x * blockDim.x + threadIdx.x;
    if (e < NE) atomicAdd(&rowptr[ei[NE + e] + 1], 1);
}

__global__ __launch_bounds__(1024) void scan_kernel(int* __restrict__ rowptr,
                                                    int* __restrict__ cursor) {
    __shared__ int sums[1024];
    const int T = 1024;
    int t = threadIdx.x;
    const int CH = (NN + T - 1) / T;
    int lo = 1 + t * CH;
    int hi = min(1 + NN, lo + CH);
    int s = 0;
    for (int i = lo; i < hi; ++i) s += rowptr[i];
    sums[t] = s;
    __syncthreads();
    for (int off = 1; off < T; off <<= 1) {
        int v = 0;
        if (t >= off) v = sums[t - off];
        __syncthreads();
        if (t >= off) sums[t] += v;
        __syncthreads();
    }
    int run = sums[t] - s;
    for (int i = lo; i < hi; ++i) {
        run += rowptr[i];
        rowptr[i] = run;
        if (i < NN) cursor[i] = run;
    }
    if (t == 0) cursor[0] = 0;
}

__global__ void fill_kernel(const int* __restrict__ ei, const float* __restrict__ ew,
                            int* __restrict__ cursor, int* __restrict__ csr_src,
                            float* __restrict__ csr_w, int* __restrict__ csr_eid) {
    int e = blockIdx.x * blockDim.x + threadIdx.x;
    if (e < NE) {
        int d = ei[NE + e];
        int pos = atomicAdd(&cursor[d], 1);
        csr_src[pos] = ei[e];
        csr_w[pos]   = ew[e];
        csr_eid[pos] = e;
    }
}

// ------------------- cast x (fp32) -> A1 cols 0..127 (bf16), coalesced -----
__global__ __launch_bounds__(256) void cast_x(const float* __restrict__ x,
                                              unsigned short* __restrict__ A1) {
    int tid = blockIdx.x * blockDim.x + threadIdx.x;   // NN*32 threads
    if (tid >= NN * 32) return;
    int n = tid >> 5, q = tid & 31;
    float4 v = *(const float4*)&x[(size_t)n * ND + q * 4];
    unsigned short o[4] = {f2b(v.x), f2b(v.y), f2b(v.z), f2b(v.w)};
    *(uint2*)&A1[(size_t)n * KP1 + q * 4] = *(uint2*)o;
}

// ---- inc: wave per node; lanes = 4 edge-groups x 16 features; shfl reduce --
// writes A1 cols 128..143 (weighted edge_attr segment sum) and pad 144..191=0
__global__ __launch_bounds__(256) void inc_kernel(
    const float* __restrict__ edge_attr,
    const int* __restrict__ rowptr,
    const float* __restrict__ csr_w,
    const int* __restrict__ csr_eid,
    unsigned short* __restrict__ A1) {
    int n = (blockIdx.x * blockDim.x + threadIdx.x) >> 6;
    int lane = threadIdx.x & 63;
    if (n >= NN) return;
    int g = lane >> 4, j = lane & 15;
    int lo = rowptr[n], hi = rowptr[n + 1];
    float v = 0.f;
    for (int k = lo + g; k < hi; k += 4) {
        float w = csr_w[k];
        int eid = csr_eid[k];
        v += w * edge_attr[(size_t)eid * ED + j];
    }
    v += __shfl_xor(v, 16);
    v += __shfl_xor(v, 32);
    if (lane < 16)
        A1[(size_t)n * KP1 + ND + lane] = f2b(v);
    else
        A1[(size_t)n * KP1 + ND + lane] = 0;   // pad cols 144..191
}

// B0T[n][k] = bf16(W0[k][n]) padded to [320][192]
__global__ void castB0(const float* __restrict__ W0, unsigned short* __restrict__ B0T) {
    int n = blockIdx.x, k = threadIdx.x;
    float v = (n < HID && k < ND + ED) ? W0[(size_t)k * HID + n] : 0.f;
    B0T[(size_t)n * KP1 + k] = f2b(v);
}

// BT[n][k] = bf16(W[k][n]) padded to [320][320]
__global__ void castB(const float* __restrict__ W, unsigned short* __restrict__ BT) {
    int n = blockIdx.x, k = threadIdx.x;
    float v = (n < HID && k < HID) ? W[(size_t)k * HID + n] : 0.f;
    BT[(size_t)n * KP2 + k] = f2b(v);
}

// ----------------------------------------------------------- MFMA bf16 GEMM
template <int MODE, int KP>
__global__ __launch_bounds__(256) void gemm_mfma(
    const unsigned short* __restrict__ A,   // [M, KP] bf16 row-major
    const unsigned short* __restrict__ BT,  // [320, KP] bf16 (B transposed)
    const float* __restrict__ bias,         // [300]
    const float* __restrict__ RES,          // MODE1: h0 [M,300] fp32
    float* __restrict__ C,                  // [M,300] fp32
    unsigned short* __restrict__ h0b,       // MODE0: [M,320] bf16
    int M)
{
    __shared__ unsigned short As[128][64];
    __shared__ unsigned short Bs[64][64];
    const int tid = threadIdx.x;
    const int m0 = blockIdx.x * 128;
    const int n0 = blockIdx.y * 64;
    const int wave = tid >> 6, lane = tid & 63;
    const int wm = wave >> 1, wn = wave & 1;
    const int quad = lane >> 4, lr = lane & 15;
    f32x4 acc[4][2] = {};

    for (int kb = 0; kb < KP; kb += 64) {
        #pragma unroll
        for (int i = 0; i < 4; ++i) {           // A tile 128x64
            int s = tid + i * 256;
            int r = s >> 3, c = (s & 7) * 8;
            int mg = m0 + r; if (mg >= M) mg = M - 1;
            *(uint4*)&As[r][c] = *(const uint4*)&A[(size_t)mg * KP + kb + c];
        }
        #pragma unroll
        for (int i = 0; i < 2; ++i) {           // B tile 64x64
            int s = tid + i * 256;
            int r = s >> 3, c = (s & 7) * 8;
            *(uint4*)&Bs[r][c] = *(const uint4*)&BT[(size_t)(n0 + r) * KP + kb + c];
        }
        __syncthreads();
        #pragma unroll
        for (int ks = 0; ks < 2; ++ks) {
            short8 a[4], b[2];
            #pragma unroll
            for (int tm = 0; tm < 4; ++tm)
                a[tm] = *(const short8*)&As[wm * 64 + tm * 16 + lr][ks * 32 + quad * 8];
            #pragma unroll
            for (int tn = 0; tn < 2; ++tn)
                b[tn] = *(const short8*)&Bs[wn * 32 + tn * 16 + lr][ks * 32 + quad * 8];
            #pragma unroll
            for (int tm = 0; tm < 4; ++tm)
                #pragma unroll
                for (int tn = 0; tn < 2; ++tn)
                    acc[tm][tn] = __builtin_amdgcn_mfma_f32_16x16x32_bf16(
                        a[tm], b[tn], acc[tm][tn], 0, 0, 0);
        }
        __syncthreads();
    }
    #pragma unroll
    for (int tm = 0; tm < 4; ++tm) {
        #pragma unroll
        for (int tn = 0; tn < 2; ++tn) {
            int ng = n0 + wn * 32 + tn * 16 + lr;
            #pragma unroll
            for (int r = 0; r < 4; ++r) {
                int mg = m0 + wm * 64 + tm * 16 + quad * 4 + r;
                if (mg < M && ng < HID) {
                    float v = acc[tm][tn][r] + bias[ng];
                    if (MODE == 1) v += RES[(size_t)mg * HID + ng];
                    v = fmaxf(v, 0.f);
                    C[(size_t)mg * HID + ng] = v;
                    if (MODE == 0) h0b[(size_t)mg * NP + ng] = f2b(v);
                }
            }
        }
    }
}

// ---------------- aggB[n] = bf16(mean_k w_k * h0b[src_k]) ------------------
__global__ __launch_bounds__(256) void agg_kernel(
    const unsigned short* __restrict__ h0b,   // [NN, 320] bf16
    const int* __restrict__ rowptr,
    const int* __restrict__ csr_src,
    const float* __restrict__ csr_w,
    unsigned short* __restrict__ aggB)        // [NN, 320] bf16, pad cols = 0
{
    int n = (blockIdx.x * blockDim.x + threadIdx.x) >> 6;
    int lane = threadIdx.x & 63;
    if (n >= NN) return;
    int lo = rowptr[n], hi = rowptr[n + 1];
    float acc[8] = {};
    const uint4* h4 = (const uint4*)h0b;      // row stride = 40 uint4
    bool act = lane < 40;
    int k = lo;
    for (; k + 1 < hi; k += 2) {
        int s0 = csr_src[k], s1 = csr_src[k + 1];
        float w0 = csr_w[k], w1 = csr_w[k + 1];
        uint4 r0 = {0, 0, 0, 0}, r1 = {0, 0, 0, 0};
        if (act) {
            r0 = h4[(size_t)s0 * 40 + lane];
            r1 = h4[(size_t)s1 * 40 + lane];
        }
        acc[0] += w0 * blo(r0.x); acc[1] += w0 * bhi(r0.x);
        acc[2] += w0 * blo(r0.y); acc[3] += w0 * bhi(r0.y);
        acc[4] += w0 * blo(r0.z); acc[5] += w0 * bhi(r0.z);
        acc[6] += w0 * blo(r0.w); acc[7] += w0 * bhi(r0.w);
        acc[0] += w1 * blo(r1.x); acc[1] += w1 * bhi(r1.x);
        acc[2] += w1 * blo(r1.y); acc[3] += w1 * bhi(r1.y);
        acc[4] += w1 * blo(r1.z); acc[5] += w1 * bhi(r1.z);
        acc[6] += w1 * blo(r1.w); acc[7] += w1 * bhi(r1.w);
    }
    if (k < hi) {
        int s0 = csr_src[k];
        float w0 = csr_w[k];
        uint4 r0 = {0, 0, 0, 0};
        if (act) r0 = h4[(size_t)s0 * 40 + lane];
        acc[0] += w0 * blo(r0.x); acc[1] += w0 * bhi(r0.x);
        acc[2] += w0 * blo(r0.y); acc[3] += w0 * bhi(r0.y);
        acc[4] += w0 * blo(r0.z); acc[5] += w0 * bhi(r0.z);
        acc[6] += w0 * blo(r0.w); acc[7] += w0 * bhi(r0.w);
    }
    if (act) {
        float invd = 1.f / fmaxf((float)(hi - lo), 1.f);
        int cbase = lane * 8;
        unsigned int o[4];
        #pragma unroll
        for (int i = 0; i < 4; ++i) {
            int c0 = cbase + 2 * i, c1 = c0 + 1;
            unsigned int ulo = (c0 < HID) ? f2b(acc[2 * i] * invd) : 0;
            unsigned int uhi = (c1 < HID) ? f2b(acc[2 * i + 1] * invd) : 0;
            o[i] = ulo | (uhi << 16);
        }
        uint4* a4 = (uint4*)aggB;
        uint4 v; v.x = o[0]; v.y = o[1]; v.z = o[2]; v.w = o[3];
        a4[(size_t)n * 40 + lane] = v;
    }
}

// ---------------------------------------------------------------- launch
extern "C" void kernel_launch(void* const* d_in, const int* in_sizes, int n_in,
                              void* d_out, int out_size, void* d_ws, size_t ws_size,
                              hipStream_t stream) {
    const float* x           = (const float*)d_in[0];
    const float* edge_attr   = (const float*)d_in[1];
    const float* edge_weight = (const float*)d_in[2];
    const float* W0 = (const float*)d_in[4];
    const float* b0 = (const float*)d_in[5];
    const float* W  = (const float*)d_in[6];
    const float* b  = (const float*)d_in[7];
    const int* ei   = (const int*)d_in[8];

    float* out = (float*)d_out;
    float* h  = out;                          // output 0: [NN, HID]
    float* h0 = out + (size_t)NN * HID;       // output 1: [NN, HID]

    char* p = (char*)d_ws;
    auto alloc = [&](size_t bytes) { char* q = p; p += (bytes + 255) & ~(size_t)255; return q; };
    int*   rowptr  = (int*)  alloc((NN + 1) * sizeof(int));
    int*   cursor  = (int*)  alloc(NN * sizeof(int));
    int*   csr_src = (int*)  alloc(NE * sizeof(int));
    float* csr_w   = (float*)alloc(NE * sizeof(float));
    int*   csr_eid = (int*)  alloc(NE * sizeof(int));
    unsigned short* A1   = (unsigned short*)alloc((size_t)NN * KP1 * 2);
    unsigned short* h0b  = (unsigned short*)alloc((size_t)NN * NP * 2);
    unsigned short* aggB = (unsigned short*)alloc((size_t)NN * NP * 2);
    unsigned short* B0T  = (unsigned short*)alloc((size_t)NP * KP1 * 2);
    unsigned short* BT   = (unsigned short*)alloc((size_t)NP * KP2 * 2);

    hipMemsetAsync(rowptr, 0, (NN + 1) * sizeof(int), stream);
    hist_kernel<<<(NE + 255) / 256, 256, 0, stream>>>(ei, rowptr);
    scan_kernel<<<1, 1024, 0, stream>>>(rowptr, cursor);
    fill_kernel<<<(NE + 255) / 256, 256, 0, stream>>>(ei, edge_weight, cursor,
                                                      csr_src, csr_w, csr_eid);
    castB0<<<NP, KP1, 0, stream>>>(W0, B0T);
    castB<<<NP, KP2, 0, stream>>>(W, BT);
    cast_x<<<(NN * 32 + 255) / 256, 256, 0, stream>>>(x, A1);
    inc_kernel<<<(NN + 3) / 4, 256, 0, stream>>>(edge_attr, rowptr, csr_w,
                                                 csr_eid, A1);

    dim3 g((NN + 127) / 128, NP / 64);
    gemm_mfma<0, KP1><<<g, 256, 0, stream>>>(A1, B0T, b0, nullptr, h0, h0b, NN);
    agg_kernel<<<(NN + 3) / 4, 256, 0, stream>>>(h0b, rowptr, csr_src, csr_w, aggB);
    gemm_mfma<1, KP2><<<g, 256, 0, stream>>>(aggB, BT, b, h0, h, nullptr, NN);
}

// Round 5
// 514.858 us; speedup vs baseline: 1.7200x; 1.1873x over previous
//
#include <hip/hip_runtime.h>

#define NN 50000      // nodes
#define NE 800000     // edges
#define ND 128        // node_attr_dim
#define ED 16         // edge_attr_dim
#define HID 300       // hidden
#define KP1 192       // padded K for gemm1 (128+16 -> 192)
#define KP2 320       // padded K for gemm2 (300 -> 320)
#define NP 320        // padded N (300 -> 320)

#define SCAN_T 256
#define SCAN_B ((NN + SCAN_T - 1) / SCAN_T)   // 196 blocks

typedef __attribute__((ext_vector_type(8))) short short8;
typedef __attribute__((ext_vector_type(4))) float f32x4;

__device__ __forceinline__ unsigned short f2b(float f) {
    unsigned int u = __float_as_uint(f);
    u = (u + 0x7FFFu + ((u >> 16) & 1u)) >> 16;   // RNE
    return (unsigned short)u;
}
__device__ __forceinline__ float blo(unsigned int u) {
    return __uint_as_float(u << 16);
}
__device__ __forceinline__ float bhi(unsigned int u) {
    return __uint_as_float(u & 0xffff0000u);
}

// in-block inclusive scan of v across 256 threads (4 waves)
__device__ __forceinline__ int block_iscan(int v, int tid) {
    int lane = tid & 63;
    #pragma unroll
    for (int off = 1; off < 64; off <<= 1) {
        int t = __shfl_up(v, off);
        if (lane >= off) v += t;
    }
    __shared__ int wsum[4];
    int wid = tid >> 6;
    if (lane == 63) wsum[wid] = v;
    __syncthreads();
    int add = 0;
    #pragma unroll
    for (int w = 0; w < 4; ++w)
        if (w < wid) add += wsum[w];
    return v + add;
}

// ---------------------------------------------------------------- CSR build
__global__ void hist_kernel(const int* __restrict__ ei, int* __restrict__ rowptr) {
    int e = blockIdx.x * blockDim.x + threadIdx.x;
    if (e < NE) atomicAdd(&rowptr[ei[NE + e] + 1], 1);
}

// phase 1: local inclusive scan of rowptr[1..NN], block totals out
__global__ __launch_bounds__(SCAN_T) void scan1(int* __restrict__ rowptr,
                                                int* __restrict__ blockSums) {
    int i = blockIdx.x * SCAN_T + threadIdx.x;
    int v = (i < NN) ? rowptr[1 + i] : 0;
    v = block_iscan(v, threadIdx.x);
    if (i < NN) rowptr[1 + i] = v;
    if (threadIdx.x == SCAN_T - 1) blockSums[blockIdx.x] = v;
}

// phase 2: exclusive scan of block totals (196 <= 256, one block)
__global__ __launch_bounds__(SCAN_T) void scan2(int* __restrict__ blockSums) {
    int t = threadIdx.x;
    int orig = (t < SCAN_B) ? blockSums[t] : 0;
    int v = block_iscan(orig, t);
    if (t < SCAN_B) blockSums[t] = v - orig;   // exclusive
}

// phase 3: add block offsets; emit cursor[] (exclusive prefix per node)
__global__ __launch_bounds__(SCAN_T) void scan3(int* __restrict__ rowptr,
                                                const int* __restrict__ blockSums,
                                                int* __restrict__ cursor) {
    int i = blockIdx.x * SCAN_T + threadIdx.x;
    if (i < NN) {
        int v = rowptr[1 + i] + blockSums[blockIdx.x];
        rowptr[1 + i] = v;
        if (i + 1 < NN) cursor[i + 1] = v;
    }
    if (i == 0) cursor[0] = 0;
}

__global__ void fill_kernel(const int* __restrict__ ei, const float* __restrict__ ew,
                            int* __restrict__ cursor, int* __restrict__ csr_src,
                            float* __restrict__ csr_w, int* __restrict__ csr_eid) {
    int e = blockIdx.x * blockDim.x + threadIdx.x;
    if (e < NE) {
        int d = ei[NE + e];
        int pos = atomicAdd(&cursor[d], 1);
        csr_src[pos] = ei[e];
        csr_w[pos]   = ew[e];
        csr_eid[pos] = e;
    }
}

// ------------------- cast x (fp32) -> A1 cols 0..127 (bf16), coalesced -----
__global__ __launch_bounds__(256) void cast_x(const float* __restrict__ x,
                                              unsigned short* __restrict__ A1) {
    int tid = blockIdx.x * blockDim.x + threadIdx.x;   // NN*32 threads
    if (tid >= NN * 32) return;
    int n = tid >> 5, q = tid & 31;
    float4 v = *(const float4*)&x[(size_t)n * ND + q * 4];
    unsigned short o[4] = {f2b(v.x), f2b(v.y), f2b(v.z), f2b(v.w)};
    *(uint2*)&A1[(size_t)n * KP1 + q * 4] = *(uint2*)o;
}

// ---- inc: wave per node; lanes = 4 edge-groups x 16 features; shfl reduce --
__global__ __launch_bounds__(256) void inc_kernel(
    const float* __restrict__ edge_attr,
    const int* __restrict__ rowptr,
    const float* __restrict__ csr_w,
    const int* __restrict__ csr_eid,
    unsigned short* __restrict__ A1) {
    int n = (blockIdx.x * blockDim.x + threadIdx.x) >> 6;
    int lane = threadIdx.x & 63;
    if (n >= NN) return;
    int g = lane >> 4, j = lane & 15;
    int lo = rowptr[n], hi = rowptr[n + 1];
    float v = 0.f;
    for (int k = lo + g; k < hi; k += 4) {
        float w = csr_w[k];
        int eid = csr_eid[k];
        v += w * edge_attr[(size_t)eid * ED + j];
    }
    v += __shfl_xor(v, 16);
    v += __shfl_xor(v, 32);
    if (lane < 16)
        A1[(size_t)n * KP1 + ND + lane] = f2b(v);
    else
        A1[(size_t)n * KP1 + ND + lane] = 0;   // pad cols 144..191
}

// B0T[n][k] = bf16(W0[k][n]) padded to [320][192]
__global__ void castB0(const float* __restrict__ W0, unsigned short* __restrict__ B0T) {
    int n = blockIdx.x, k = threadIdx.x;
    float v = (n < HID && k < ND + ED) ? W0[(size_t)k * HID + n] : 0.f;
    B0T[(size_t)n * KP1 + k] = f2b(v);
}

// BT[n][k] = bf16(W[k][n]) padded to [320][320]
__global__ void castB(const float* __restrict__ W, unsigned short* __restrict__ BT) {
    int n = blockIdx.x, k = threadIdx.x;
    float v = (n < HID && k < HID) ? W[(size_t)k * HID + n] : 0.f;
    BT[(size_t)n * KP2 + k] = f2b(v);
}

// ----------------------------------------------------------- MFMA bf16 GEMM
template <int MODE, int KP>
__global__ __launch_bounds__(256) void gemm_mfma(
    const unsigned short* __restrict__ A,   // [M, KP] bf16 row-major
    const unsigned short* __restrict__ BT,  // [320, KP] bf16 (B transposed)
    const float* __restrict__ bias,         // [300]
    const float* __restrict__ RES,          // MODE1: h0 [M,300] fp32
    float* __restrict__ C,                  // [M,300] fp32
    unsigned short* __restrict__ h0b,       // MODE0: [M,320] bf16
    int M)
{
    __shared__ unsigned short As[128][64];
    __shared__ unsigned short Bs[64][64];
    const int tid = threadIdx.x;
    const int m0 = blockIdx.x * 128;
    const int n0 = blockIdx.y * 64;
    const int wave = tid >> 6, lane = tid & 63;
    const int wm = wave >> 1, wn = wave & 1;
    const int quad = lane >> 4, lr = lane & 15;
    f32x4 acc[4][2] = {};

    for (int kb = 0; kb < KP; kb += 64) {
        #pragma unroll
        for (int i = 0; i < 4; ++i) {           // A tile 128x64
            int s = tid + i * 256;
            int r = s >> 3, c = (s & 7) * 8;
            int mg = m0 + r; if (mg >= M) mg = M - 1;
            *(uint4*)&As[r][c] = *(const uint4*)&A[(size_t)mg * KP + kb + c];
        }
        #pragma unroll
        for (int i = 0; i < 2; ++i) {           // B tile 64x64
            int s = tid + i * 256;
            int r = s >> 3, c = (s & 7) * 8;
            *(uint4*)&Bs[r][c] = *(const uint4*)&BT[(size_t)(n0 + r) * KP + kb + c];
        }
        __syncthreads();
        #pragma unroll
        for (int ks = 0; ks < 2; ++ks) {
            short8 a[4], b[2];
            #pragma unroll
            for (int tm = 0; tm < 4; ++tm)
                a[tm] = *(const short8*)&As[wm * 64 + tm * 16 + lr][ks * 32 + quad * 8];
            #pragma unroll
            for (int tn = 0; tn < 2; ++tn)
                b[tn] = *(const short8*)&Bs[wn * 32 + tn * 16 + lr][ks * 32 + quad * 8];
            #pragma unroll
            for (int tm = 0; tm < 4; ++tm)
                #pragma unroll
                for (int tn = 0; tn < 2; ++tn)
                    acc[tm][tn] = __builtin_amdgcn_mfma_f32_16x16x32_bf16(
                        a[tm], b[tn], acc[tm][tn], 0, 0, 0);
        }
        __syncthreads();
    }
    #pragma unroll
    for (int tm = 0; tm < 4; ++tm) {
        #pragma unroll
        for (int tn = 0; tn < 2; ++tn) {
            int ng = n0 + wn * 32 + tn * 16 + lr;
            #pragma unroll
            for (int r = 0; r < 4; ++r) {
                int mg = m0 + wm * 64 + tm * 16 + quad * 4 + r;
                if (mg < M && ng < HID) {
                    float v = acc[tm][tn][r] + bias[ng];
                    if (MODE == 1) v += RES[(size_t)mg * HID + ng];
                    v = fmaxf(v, 0.f);
                    C[(size_t)mg * HID + ng] = v;
                    if (MODE == 0) h0b[(size_t)mg * NP + ng] = f2b(v);
                }
            }
        }
    }
}

// ---------------- aggB[n] = bf16(mean_k w_k * h0b[src_k]) ------------------
__global__ __launch_bounds__(256) void agg_kernel(
    const unsigned short* __restrict__ h0b,   // [NN, 320] bf16
    const int* __restrict__ rowptr,
    const int* __restrict__ csr_src,
    const float* __restrict__ csr_w,
    unsigned short* __restrict__ aggB)        // [NN, 320] bf16, pad cols = 0
{
    int n = (blockIdx.x * blockDim.x + threadIdx.x) >> 6;
    int lane = threadIdx.x & 63;
    if (n >= NN) return;
    int lo = rowptr[n], hi = rowptr[n + 1];
    float acc[8] = {};
    const uint4* h4 = (const uint4*)h0b;      // row stride = 40 uint4
    bool act = lane < 40;
    int k = lo;
    for (; k + 1 < hi; k += 2) {
        int s0 = csr_src[k], s1 = csr_src[k + 1];
        float w0 = csr_w[k], w1 = csr_w[k + 1];
        uint4 r0 = {0, 0, 0, 0}, r1 = {0, 0, 0, 0};
        if (act) {
            r0 = h4[(size_t)s0 * 40 + lane];
            r1 = h4[(size_t)s1 * 40 + lane];
        }
        acc[0] += w0 * blo(r0.x); acc[1] += w0 * bhi(r0.x);
        acc[2] += w0 * blo(r0.y); acc[3] += w0 * bhi(r0.y);
        acc[4] += w0 * blo(r0.z); acc[5] += w0 * bhi(r0.z);
        acc[6] += w0 * blo(r0.w); acc[7] += w0 * bhi(r0.w);
        acc[0] += w1 * blo(r1.x); acc[1] += w1 * bhi(r1.x);
        acc[2] += w1 * blo(r1.y); acc[3] += w1 * bhi(r1.y);
        acc[4] += w1 * blo(r1.z); acc[5] += w1 * bhi(r1.z);
        acc[6] += w1 * blo(r1.w); acc[7] += w1 * bhi(r1.w);
    }
    if (k < hi) {
        int s0 = csr_src[k];
        float w0 = csr_w[k];
        uint4 r0 = {0, 0, 0, 0};
        if (act) r0 = h4[(size_t)s0 * 40 + lane];
        acc[0] += w0 * blo(r0.x); acc[1] += w0 * bhi(r0.x);
        acc[2] += w0 * blo(r0.y); acc[3] += w0 * bhi(r0.y);
        acc[4] += w0 * blo(r0.z); acc[5] += w0 * bhi(r0.z);
        acc[6] += w0 * blo(r0.w); acc[7] += w0 * bhi(r0.w);
    }
    if (act) {
        float invd = 1.f / fmaxf((float)(hi - lo), 1.f);
        int cbase = lane * 8;
        unsigned int o[4];
        #pragma unroll
        for (int i = 0; i < 4; ++i) {
            int c0 = cbase + 2 * i, c1 = c0 + 1;
            unsigned int ulo = (c0 < HID) ? f2b(acc[2 * i] * invd) : 0;
            unsigned int uhi = (c1 < HID) ? f2b(acc[2 * i + 1] * invd) : 0;
            o[i] = ulo | (uhi << 16);
        }
        uint4* a4 = (uint4*)aggB;
        uint4 v; v.x = o[0]; v.y = o[1]; v.z = o[2]; v.w = o[3];
        a4[(size_t)n * 40 + lane] = v;
    }
}

// ---------------------------------------------------------------- launch
extern "C" void kernel_launch(void* const* d_in, const int* in_sizes, int n_in,
                              void* d_out, int out_size, void* d_ws, size_t ws_size,
                              hipStream_t stream) {
    const float* x           = (const float*)d_in[0];
    const float* edge_attr   = (const float*)d_in[1];
    const float* edge_weight = (const float*)d_in[2];
    const float* W0 = (const float*)d_in[4];
    const float* b0 = (const float*)d_in[5];
    const float* W  = (const float*)d_in[6];
    const float* b  = (const float*)d_in[7];
    const int* ei   = (const int*)d_in[8];

    float* out = (float*)d_out;
    float* h  = out;                          // output 0: [NN, HID]
    float* h0 = out + (size_t)NN * HID;       // output 1: [NN, HID]

    char* p = (char*)d_ws;
    auto alloc = [&](size_t bytes) { char* q = p; p += (bytes + 255) & ~(size_t)255; return q; };
    int*   rowptr  = (int*)  alloc((NN + 1) * sizeof(int));
    int*   cursor  = (int*)  alloc(NN * sizeof(int));
    int*   bsums   = (int*)  alloc(SCAN_B * sizeof(int));
    int*   csr_src = (int*)  alloc(NE * sizeof(int));
    float* csr_w   = (float*)alloc(NE * sizeof(float));
    int*   csr_eid = (int*)  alloc(NE * sizeof(int));
    unsigned short* A1   = (unsigned short*)alloc((size_t)NN * KP1 * 2);
    unsigned short* h0b  = (unsigned short*)alloc((size_t)NN * NP * 2);
    unsigned short* aggB = (unsigned short*)alloc((size_t)NN * NP * 2);
    unsigned short* B0T  = (unsigned short*)alloc((size_t)NP * KP1 * 2);
    unsigned short* BT   = (unsigned short*)alloc((size_t)NP * KP2 * 2);

    hipMemsetAsync(rowptr, 0, (NN + 1) * sizeof(int), stream);
    hist_kernel<<<(NE + 255) / 256, 256, 0, stream>>>(ei, rowptr);
    scan1<<<SCAN_B, SCAN_T, 0, stream>>>(rowptr, bsums);
    scan2<<<1, SCAN_T, 0, stream>>>(bsums);
    scan3<<<SCAN_B, SCAN_T, 0, stream>>>(rowptr, bsums, cursor);
    fill_kernel<<<(NE + 255) / 256, 256, 0, stream>>>(ei, edge_weight, cursor,
                                                      csr_src, csr_w, csr_eid);
    castB0<<<NP, KP1, 0, stream>>>(W0, B0T);
    castB<<<NP, KP2, 0, stream>>>(W, BT);
    cast_x<<<(NN * 32 + 255) / 256, 256, 0, stream>>>(x, A1);
    inc_kernel<<<(NN + 3) / 4, 256, 0, stream>>>(edge_attr, rowptr, csr_w,
                                                 csr_eid, A1);

    dim3 g((NN + 127) / 128, NP / 64);
    gemm_mfma<0, KP1><<<g, 256, 0, stream>>>(A1, B0T, b0, nullptr, h0, h0b, NN);
    agg_kernel<<<(NN + 3) / 4, 256, 0, stream>>>(h0b, rowptr, csr_src, csr_w, aggB);
    gemm_mfma<1, KP2><<<g, 256, 0, stream>>>(aggB, BT, b, h0, h, nullptr, NN);
}